// Round 2
// baseline (7513.831 us; speedup 1.0000x reference)
//
#include <hip/hip_runtime.h>

// LSTM B=64 T=256 I=512 H=1024, fp32 in/out, fp16 MFMA compute (fp32 accum).
// Round 1: bf16 -> fp16 (8x less rounding error, same speed/layout).
//
// Layouts in d_ws:
//   Wp   [64 wg][64 col][1536 k] fp16  — col = gate*16 + unit_local; k = [W_h row | W_x row]
//   xh   [64 b][256 t][512 i]    fp16
//   bias [4][1024] fp32  (b_x + b_h + w_B + b_B)
//   hbuf [2][64 b][1024 u] fp16  (double-buffered recurrent state)
//   cst  [64 b][1024 u] fp32

using f32x4 = __attribute__((ext_vector_type(4))) float;
using u32x4 = __attribute__((ext_vector_type(4))) unsigned int;
using u32x2 = __attribute__((ext_vector_type(2))) unsigned int;

#define NB   64
#define NT   256
#define NI   512
#define NH   1024
#define KTOT 1536   // NH + NI

#define OFF_WP    0u
#define SZ_WP     (64u*64u*1536u*2u)          // 12,582,912
#define OFF_XBF   (OFF_WP + SZ_WP)
#define SZ_XBF    (64u*256u*512u*2u)          // 16,777,216
#define OFF_BIAS  (OFF_XBF + SZ_XBF)
#define SZ_BIAS   (4096u*4u)
#define OFF_HBUF  (OFF_BIAS + SZ_BIAS)
#define SZ_HBUF   (2u*64u*1024u*2u)
#define OFF_C     (OFF_HBUF + SZ_HBUF)
#define SZ_C      (64u*1024u*4u)

__device__ __forceinline__ unsigned short f2h(float f) {
  _Float16 h = (_Float16)f;                    // v_cvt_f16_f32, RTN
  return __builtin_bit_cast(unsigned short, h);
}

__device__ __forceinline__ float sigmoid_f(float x) {
  // exp(-x) -> inf for very negative x gives 1/(1+inf)=0: safe, no NaN.
  return 1.0f / (1.0f + __expf(-x));
}
__device__ __forceinline__ float tanh_f(float x) {
  float xc = fminf(fmaxf(x, -15.0f), 15.0f);   // e^30 finite, no inf/inf NaN
  float e = __expf(2.0f * xc);
  return 1.0f - 2.0f / (e + 1.0f);
}

// ---------------- prep kernels ----------------

__global__ __launch_bounds__(256) void pack_w_kernel(
    const float* __restrict__ W_h, const float* __restrict__ W_x,
    unsigned short* __restrict__ Wp) {
  int gid = blockIdx.x * 256 + threadIdx.x;     // one thread = 4 consecutive k
  int base = gid * 4;
  if (base >= 64 * 64 * 1536) return;
  int row  = base / 1536;                       // wg*64 + col
  int k    = base - row * 1536;
  int col  = row & 63;
  int wg   = row >> 6;
  int unit = (wg << 4) + (col & 15);
  int gate = col >> 4;
  const float* srcH = W_h + (size_t)(gate * 1024 + unit) * 1024;
  const float* srcX = W_x + (size_t)(gate * 1024 + unit) * 512;
  unsigned short v[4];
#pragma unroll
  for (int j = 0; j < 4; ++j) {
    int kk = k + j;
    float f = (kk < NH) ? srcH[kk] : srcX[kk - NH];
    v[j] = f2h(f);
  }
  u32x2 o;
  o[0] = (unsigned int)v[0] | ((unsigned int)v[1] << 16);
  o[1] = (unsigned int)v[2] | ((unsigned int)v[3] << 16);
  *(u32x2*)(Wp + base) = o;
}

__global__ __launch_bounds__(256) void pack_x_kernel(
    const float* __restrict__ x, unsigned short* __restrict__ xh) {
  int gid = blockIdx.x * 256 + threadIdx.x;
  int base = gid * 4;
  if (base >= NB * NT * NI) return;
  const float* s = x + base;
  u32x2 o;
  unsigned short v0 = f2h(s[0]), v1 = f2h(s[1]), v2 = f2h(s[2]), v3 = f2h(s[3]);
  o[0] = (unsigned int)v0 | ((unsigned int)v1 << 16);
  o[1] = (unsigned int)v2 | ((unsigned int)v3 << 16);
  *(u32x2*)(xh + base) = o;
}

__global__ __launch_bounds__(256) void prep_small_kernel(
    const float* __restrict__ b_x, const float* __restrict__ b_h,
    const float* __restrict__ w_B, const float* __restrict__ b_B,
    float* __restrict__ bias, unsigned short* __restrict__ hbuf,
    float* __restrict__ cst) {
  int gid = blockIdx.x * 256 + threadIdx.x;
  if (gid < 4096) bias[gid] = b_x[gid] + b_h[gid] + w_B[gid] + b_B[gid];
  int j = gid - 4096;
  if (j >= 0 && j < NB * NH) {
    cst[j] = 0.0f;
    hbuf[j] = 0;
    hbuf[NB * NH + j] = 0;
  }
}

// ---------------- per-timestep kernel ----------------
// Grid: 64 WGs x 256 threads. WG wg owns units [wg*16, wg*16+16), all 64 batches.
// Wave = row-tile (16 batches), computes 4 gate-tiles of G[16 x 16] via MFMA.
// Lane layout (16x16x32 f16): A: lane&15 = row(m), lane>>4 selects k-chunk of 8.
// B: lane&15 = col(n), same k-chunking.  D: col = lane&15, row = (lane>>4)*4 + reg.

__global__ __launch_bounds__(256) void lstm_step(
    const unsigned short* __restrict__ Wp,
    const unsigned short* __restrict__ xh,
    const float* __restrict__ bias,
    const unsigned short* __restrict__ h_prev,
    unsigned short* __restrict__ h_next,
    float* __restrict__ c_st,
    float* __restrict__ out,
    int t) {
  const int wg   = blockIdx.x;
  const int tid  = threadIdx.x;
  const int wave = tid >> 6;
  const int lane = tid & 63;
  const int l15  = lane & 15;
  const int kg   = lane >> 4;
  const int u0   = wg << 4;

  f32x4 acc[4];
#pragma unroll
  for (int g = 0; g < 4; ++g) {
    float bv = bias[g * 1024 + u0 + l15];
    acc[g] = (f32x4){bv, bv, bv, bv};
  }

  const int arow = (wave << 4) + l15;   // A-fragment batch row
  const unsigned short* hrow = h_prev + arow * NH + kg * 8;
  const unsigned short* xrow = xh + ((size_t)(arow * NT + t)) * NI + kg * 8;
  const unsigned short* wrow = Wp + (size_t)(wg * 64 + l15) * KTOT + kg * 8;
  // gate stride in Wp: 16 rows * 1536 = 24576 elements

  asm volatile("s_nop 1\ns_nop 1" ::);   // VALU(bias init) -> MFMA srcC hazard guard

  // h-part: k = 0..1023 (kc 0..31)
#pragma unroll 2
  for (int kc = 0; kc < 32; ++kc) {
    u32x4 a  = *(const u32x4*)(hrow + kc * 32);
    u32x4 b0 = *(const u32x4*)(wrow + 0 * 24576 + kc * 32);
    u32x4 b1 = *(const u32x4*)(wrow + 1 * 24576 + kc * 32);
    u32x4 b2 = *(const u32x4*)(wrow + 2 * 24576 + kc * 32);
    u32x4 b3 = *(const u32x4*)(wrow + 3 * 24576 + kc * 32);
    asm("v_mfma_f32_16x16x32_f16 %0, %1, %2, %0" : "+v"(acc[0]) : "v"(a), "v"(b0));
    asm("v_mfma_f32_16x16x32_f16 %0, %1, %2, %0" : "+v"(acc[1]) : "v"(a), "v"(b1));
    asm("v_mfma_f32_16x16x32_f16 %0, %1, %2, %0" : "+v"(acc[2]) : "v"(a), "v"(b2));
    asm("v_mfma_f32_16x16x32_f16 %0, %1, %2, %0" : "+v"(acc[3]) : "v"(a), "v"(b3));
  }
  // x-part: k = 1024..1535 (kc 0..15)
#pragma unroll 2
  for (int kc = 0; kc < 16; ++kc) {
    u32x4 a  = *(const u32x4*)(xrow + kc * 32);
    u32x4 b0 = *(const u32x4*)(wrow + NH + 0 * 24576 + kc * 32);
    u32x4 b1 = *(const u32x4*)(wrow + NH + 1 * 24576 + kc * 32);
    u32x4 b2 = *(const u32x4*)(wrow + NH + 2 * 24576 + kc * 32);
    u32x4 b3 = *(const u32x4*)(wrow + NH + 3 * 24576 + kc * 32);
    asm("v_mfma_f32_16x16x32_f16 %0, %1, %2, %0" : "+v"(acc[0]) : "v"(a), "v"(b0));
    asm("v_mfma_f32_16x16x32_f16 %0, %1, %2, %0" : "+v"(acc[1]) : "v"(a), "v"(b1));
    asm("v_mfma_f32_16x16x32_f16 %0, %1, %2, %0" : "+v"(acc[2]) : "v"(a), "v"(b2));
    asm("v_mfma_f32_16x16x32_f16 %0, %1, %2, %0" : "+v"(acc[3]) : "v"(a), "v"(b3));
  }

  asm volatile("s_nop 7\ns_nop 7\ns_nop 7" ::);   // MFMA write -> VALU read hazard guard

  const int unit = u0 + l15;
#pragma unroll
  for (int r = 0; r < 4; ++r) {
    const int b = (wave << 4) + (kg << 2) + r;   // D row = kg*4 + reg
    float f  = sigmoid_f(acc[0][r]);
    float ig = sigmoid_f(acc[1][r]);
    float cb = tanh_f(acc[2][r]);
    float o  = sigmoid_f(acc[3][r]);
    float cp = c_st[b * NH + unit];
    float cn = f * cp + ig * cb;
    float hn = o * tanh_f(cn);
    c_st[b * NH + unit] = cn;
    h_next[b * NH + unit] = f2h(hn);
    out[((size_t)(b * NT + t)) * NH + unit] = hn;
  }
}

// ---------------- host launcher ----------------

extern "C" void kernel_launch(void* const* d_in, const int* in_sizes, int n_in,
                              void* d_out, int out_size, void* d_ws, size_t ws_size,
                              hipStream_t stream) {
  (void)in_sizes; (void)n_in; (void)out_size; (void)ws_size;
  const float* x   = (const float*)d_in[0];
  const float* W_x = (const float*)d_in[1];
  const float* b_x = (const float*)d_in[2];
  const float* W_h = (const float*)d_in[3];
  const float* b_h = (const float*)d_in[4];
  const float* w_B = (const float*)d_in[5];
  const float* b_B = (const float*)d_in[6];
  float* out = (float*)d_out;

  char* ws = (char*)d_ws;
  unsigned short* Wp   = (unsigned short*)(ws + OFF_WP);
  unsigned short* xh   = (unsigned short*)(ws + OFF_XBF);
  float*          bias = (float*)(ws + OFF_BIAS);
  unsigned short* hbuf = (unsigned short*)(ws + OFF_HBUF);
  float*          cst  = (float*)(ws + OFF_C);

  pack_w_kernel<<<dim3(6144), dim3(256), 0, stream>>>(W_h, W_x, Wp);
  pack_x_kernel<<<dim3(8192), dim3(256), 0, stream>>>(x, xh);
  prep_small_kernel<<<dim3(272), dim3(256), 0, stream>>>(b_x, b_h, w_B, b_B, bias, hbuf, cst);

  for (int t = 0; t < NT; ++t) {
    unsigned short* hp = hbuf + (size_t)(t & 1) * (NB * NH);
    unsigned short* hn = hbuf + (size_t)((t + 1) & 1) * (NB * NH);
    lstm_step<<<dim3(64), dim3(256), 0, stream>>>(Wp, xh, bias, hp, hn, cst, out, t);
  }
}

// Round 3
// 5009.473 us; speedup vs baseline: 1.4999x; 1.4999x over previous
//
#include <hip/hip_runtime.h>

// LSTM B=64 T=256 I=512 H=1024, fp32 in/out, fp16 MFMA compute (fp32 accum).
// Round 2: single persistent kernel. 256 WGs = (4 batch-tiles x 64 unit-groups).
// W_h fragments in VGPRs (loaded once), W_x in LDS (staged once), h exchanged
// cross-WG per step via LLC-coherent (sc0 sc1) loads/stores + flag sync.

using f32x4 = __attribute__((ext_vector_type(4))) float;
using u32x4 = __attribute__((ext_vector_type(4))) unsigned int;

#define NB 64
#define NT 256
#define NI 512
#define NH 1024

// ---- workspace layout (bytes) ----
#define OFF_WHH  0u
#define SZ_WHH   (4u*1024u*1024u*2u)        // 8,388,608  fp16 [4][1024 u_out][1024 k]
#define OFF_WXH  (OFF_WHH + SZ_WHH)
#define SZ_WXH   (4u*1024u*512u*2u)         // 4,194,304  fp16 [4][1024 u_out][512 k]
#define OFF_XH   (OFF_WXH + SZ_WXH)
#define SZ_XH    (256u*64u*512u*2u)         // 16,777,216 fp16 [T][B][I]
#define OFF_BIAS (OFF_XH + SZ_XH)
#define SZ_BIAS  (4096u*4u)
#define OFF_HG   (OFF_BIAS + SZ_BIAS)
#define SZ_HG    (2u*4u*16u*1024u*2u)       // 262,144    fp16 [2 buf][4 bt][16 b][1024 u]
#define OFF_FLG  (OFF_HG + SZ_HG)
#define SZ_FLG   (256u*4u*64u*4u)           // 262,144    u32 [T][4 bt][64 ug]

// ---- LDS layout (bytes) ----
#define L_H    0        // 16 rows x 2048 B (fp16 [16 b][1024 k], XOR-swizzled)
#define L_WX   32768    // 64 rows x 1024 B (fp16 [g*16+u][512 k], XOR-swizzled)
#define L_ACC  98304    // fp32 [4 g][16 b][16 u]
#define L_HOUT 102400   // fp16 [16 b][16 u]
#define LDS_TOTAL 102912

__device__ __forceinline__ unsigned short f2h(float f) {
  _Float16 h = (_Float16)f;
  return __builtin_bit_cast(unsigned short, h);
}
__device__ __forceinline__ float sigmoid_f(float x) {
  return 1.0f / (1.0f + __expf(-x));
}
__device__ __forceinline__ float tanh_f(float x) {
  float xc = fminf(fmaxf(x, -15.0f), 15.0f);
  float e = __expf(2.0f * xc);
  return 1.0f - 2.0f / (e + 1.0f);
}

// ---------------- prep kernels ----------------

__global__ __launch_bounds__(256) void pack_w_kernel(
    const float* __restrict__ Wh, const float* __restrict__ Wx,
    unsigned short* __restrict__ WhP, unsigned short* __restrict__ WxP) {
  int base = (blockIdx.x * 256 + threadIdx.x) * 4;
  const int nWh = 4 * 1024 * 1024;
  const int nWx = 4 * 1024 * 512;
  if (base < nWh) {
    const float* s = Wh + base;
    unsigned int o0 = (unsigned int)f2h(s[0]) | ((unsigned int)f2h(s[1]) << 16);
    unsigned int o1 = (unsigned int)f2h(s[2]) | ((unsigned int)f2h(s[3]) << 16);
    ((unsigned int*)(WhP + base))[0] = o0;
    ((unsigned int*)(WhP + base))[1] = o1;
  } else {
    int b2 = base - nWh;
    if (b2 < nWx) {
      const float* s = Wx + b2;
      unsigned int o0 = (unsigned int)f2h(s[0]) | ((unsigned int)f2h(s[1]) << 16);
      unsigned int o1 = (unsigned int)f2h(s[2]) | ((unsigned int)f2h(s[3]) << 16);
      ((unsigned int*)(WxP + b2))[0] = o0;
      ((unsigned int*)(WxP + b2))[1] = o1;
    }
  }
}

// transpose x[B][T][I] fp32 -> xh[T][B][I] fp16
__global__ __launch_bounds__(256) void pack_x_kernel(
    const float* __restrict__ x, unsigned short* __restrict__ xh) {
  int gid = blockIdx.x * 256 + threadIdx.x;     // over B*T*(I/8) = 1,048,576
  int i8 = gid & 63;
  int t  = (gid >> 6) & 255;
  int b  = gid >> 14;
  const float* s = x + (((size_t)b * NT + t) * NI + i8 * 8);
  unsigned int w[4];
#pragma unroll
  for (int j = 0; j < 4; ++j)
    w[j] = (unsigned int)f2h(s[2*j]) | ((unsigned int)f2h(s[2*j+1]) << 16);
  u32x4 v = {w[0], w[1], w[2], w[3]};
  *(u32x4*)(xh + (((size_t)t * NB + b) * NI + i8 * 8)) = v;
}

__global__ __launch_bounds__(256) void prep_small_kernel(
    const float* __restrict__ b_x, const float* __restrict__ b_h,
    const float* __restrict__ w_B, const float* __restrict__ b_B,
    float* __restrict__ bias, unsigned int* __restrict__ flags) {
  int gid = blockIdx.x * 256 + threadIdx.x;
  if (gid < 4096) bias[gid] = b_x[gid] + b_h[gid] + w_B[gid] + b_B[gid];
  if (gid < 65536)
    __hip_atomic_store(&flags[gid], 0u, __ATOMIC_RELAXED, __HIP_MEMORY_SCOPE_AGENT);
}

// ---------------- persistent LSTM kernel ----------------
// Block (bt, ug): 16 batches [bt*16..), 16 units [ug*16..), 4 gates.
// Wave g handles gate g: one 16x16 MFMA tile, K = 1024 (h) + 512 (x).
// MFMA 16x16x32 f16: A lane&15=row(batch), lane>>4=k-chunk; B lane&15=col(unit);
// D col=lane&15, row=(lane>>4)*4+reg.

__global__ __launch_bounds__(256, 1) void lstm_persist(
    const unsigned short* __restrict__ Whh,
    const unsigned short* __restrict__ Wxh,
    const unsigned short* __restrict__ xh,
    const float* __restrict__ bias,
    unsigned short* __restrict__ hglob,
    unsigned int* __restrict__ flags,
    float* __restrict__ out) {
  extern __shared__ char smem[];
  const int bid  = blockIdx.x;
  const int bt   = bid & 3;
  const int ug   = bid >> 2;
  const int tid  = threadIdx.x;
  const int g    = tid >> 6;        // wave index = gate
  const int lane = tid & 63;
  const int l15  = lane & 15;
  const int kg   = lane >> 4;

  // ---- W_h B-fragments into registers (once) ----
  u32x4 bh[32];
  {
    const unsigned short* wr = Whh + ((size_t)(g * 1024 + ug * 16 + l15)) * 1024 + kg * 8;
#pragma unroll
    for (int kc = 0; kc < 32; ++kc) bh[kc] = *(const u32x4*)(wr + kc * 32);
  }
  // ---- W_x into LDS (once, swizzled) ----
  {
    int r = tid >> 2, seg = tid & 3;           // r = g'*16+u' (0..63)
    int gg = r >> 4, uu = r & 15;
    const unsigned short* wsrc = Wxh + ((size_t)(gg * 1024 + ug * 16 + uu)) * 512;
    char* row = smem + L_WX + r * 1024;
    int sw = (r & 7) << 4;
#pragma unroll
    for (int j = 0; j < 16; ++j) {
      int chunk = seg * 16 + j;                // 64 x 16B chunks per row
      u32x4 v = *(const u32x4*)(wsrc + chunk * 8);
      *(u32x4*)(row + ((chunk * 16) ^ sw)) = v;
    }
  }
  const float bv = bias[g * 1024 + ug * 16 + l15];
  __syncthreads();

  const int eb = tid >> 4;   // epilogue batch-local
  const int eu = tid & 15;   // epilogue unit-local
  float c_reg = 0.0f;

  float* accl = (float*)(smem + L_ACC);
  unsigned short* houtl = (unsigned short*)(smem + L_HOUT);

  for (int t = 0; t < NT; ++t) {
    const int buf = t & 1, pbuf = buf ^ 1;
    if (t > 0) {
      // ---- wait for h(t-1) slices from all 64 producers of this bt ----
      const unsigned int* fl = flags + ((t - 1) * 4 + bt) * 64;
      while (true) {
        unsigned int fv = __hip_atomic_load(&fl[lane], __ATOMIC_RELAXED, __HIP_MEMORY_SCOPE_AGENT);
        if (__all(fv != 0)) break;
        __builtin_amdgcn_s_sleep(2);
      }
      __builtin_amdgcn_fence(__ATOMIC_ACQUIRE, "agent");
      // ---- stage h(t-1) -> LDS (LLC-coherent loads, XOR-swizzled writes) ----
      const int sb = tid >> 4, sc = tid & 15;
      const unsigned short* hp = hglob + ((size_t)(pbuf * 4 + bt) * 16 + sb) * 1024 + sc * 8;
      u32x4 v0, v1, v2, v3, v4, v5, v6, v7;
      asm volatile(
          "global_load_dwordx4 %0, %[p], off sc0 sc1\n\t"
          "global_load_dwordx4 %1, %[p], off offset:256 sc0 sc1\n\t"
          "global_load_dwordx4 %2, %[p], off offset:512 sc0 sc1\n\t"
          "global_load_dwordx4 %3, %[p], off offset:768 sc0 sc1\n\t"
          "global_load_dwordx4 %4, %[p], off offset:1024 sc0 sc1\n\t"
          "global_load_dwordx4 %5, %[p], off offset:1280 sc0 sc1\n\t"
          "global_load_dwordx4 %6, %[p], off offset:1536 sc0 sc1\n\t"
          "global_load_dwordx4 %7, %[p], off offset:1792 sc0 sc1\n\t"
          "s_waitcnt vmcnt(0)"
          : "=&v"(v0), "=&v"(v1), "=&v"(v2), "=&v"(v3),
            "=&v"(v4), "=&v"(v5), "=&v"(v6), "=&v"(v7)
          : [p] "v"(hp)
          : "memory");
      char* hrow = smem + L_H + sb * 2048;
      const int sw = (sb & 7) << 4;
      *(u32x4*)(hrow + ((sc * 16 +    0) ^ sw)) = v0;
      *(u32x4*)(hrow + ((sc * 16 +  256) ^ sw)) = v1;
      *(u32x4*)(hrow + ((sc * 16 +  512) ^ sw)) = v2;
      *(u32x4*)(hrow + ((sc * 16 +  768) ^ sw)) = v3;
      *(u32x4*)(hrow + ((sc * 16 + 1024) ^ sw)) = v4;
      *(u32x4*)(hrow + ((sc * 16 + 1280) ^ sw)) = v5;
      *(u32x4*)(hrow + ((sc * 16 + 1536) ^ sw)) = v6;
      *(u32x4*)(hrow + ((sc * 16 + 1792) ^ sw)) = v7;
    }
    __syncthreads();

    f32x4 acc = {bv, bv, bv, bv};
    asm volatile("s_nop 1\ns_nop 1" ::);   // VALU -> MFMA srcC hazard guard

    // ---- x-part: K = 512, B-frags from LDS ----
    {
      const unsigned short* xp = xh + ((size_t)t * NB + bt * 16 + l15) * NI + kg * 8;
      const char* wxrow = smem + L_WX + (g * 16 + l15) * 1024;
      const int sw = (l15 & 7) << 4;
#pragma unroll
      for (int kc = 0; kc < 16; ++kc) {
        u32x4 a = *(const u32x4*)(xp + kc * 32);
        u32x4 b = *(const u32x4*)(wxrow + ((kc * 64 + kg * 16) ^ sw));
        asm("v_mfma_f32_16x16x32_f16 %0, %1, %2, %0" : "+v"(acc) : "v"(a), "v"(b));
      }
    }
    // ---- h-part: K = 1024, B-frags from registers ----
    if (t > 0) {
      const char* hbase = smem + L_H + l15 * 2048;
      const int sw = (l15 & 7) << 4;
#pragma unroll
      for (int kc = 0; kc < 32; ++kc) {
        u32x4 a = *(const u32x4*)(hbase + ((kc * 64 + kg * 16) ^ sw));
        asm("v_mfma_f32_16x16x32_f16 %0, %1, %2, %0" : "+v"(acc) : "v"(a), "v"(bh[kc]));
      }
    }
    asm volatile("s_nop 7\ns_nop 7\ns_nop 7" ::);  // MFMA -> VALU hazard guard

    // ---- gate exchange through LDS: acc_lds[g][b][u] ----
#pragma unroll
    for (int r = 0; r < 4; ++r)
      accl[g * 256 + (kg * 4 + r) * 16 + l15] = acc[r];
    __syncthreads();

    // ---- pointwise epilogue: thread -> (eb, eu) ----
    {
      float gf = accl[0 * 256 + eb * 16 + eu];
      float gi = accl[1 * 256 + eb * 16 + eu];
      float gc = accl[2 * 256 + eb * 16 + eu];
      float go = accl[3 * 256 + eb * 16 + eu];
      float f  = sigmoid_f(gf);
      float i  = sigmoid_f(gi);
      float cb = tanh_f(gc);
      float o  = sigmoid_f(go);
      float cn = f * c_reg + i * cb;
      c_reg = cn;
      float hn = o * tanh_f(cn);
      out[(((size_t)(bt * 16 + eb)) * NT + t) * NH + ug * 16 + eu] = hn;
      houtl[eb * 16 + eu] = f2h(hn);
    }
    __syncthreads();

    // ---- publish h(t) slice (LLC-coherent) + flag ----
    if (tid < 32) {
      u32x4 hv = *(const u32x4*)(houtl + tid * 8);   // 8 fp16 = 16 B
      unsigned short* dst = hglob + ((size_t)(buf * 4 + bt) * 16 + (tid >> 1)) * 1024
                          + ug * 16 + (tid & 1) * 8;
      asm volatile("global_store_dwordx4 %[p], %[v], off sc0 sc1\n\t"
                   "s_waitcnt vmcnt(0)"
                   :: [p] "v"(dst), [v] "v"(hv) : "memory");
    }
    __syncthreads();
    if (tid == 0)
      __hip_atomic_store(&flags[(t * 4 + bt) * 64 + ug], 1u,
                         __ATOMIC_RELEASE, __HIP_MEMORY_SCOPE_AGENT);
  }
}

// ---------------- host launcher ----------------

extern "C" void kernel_launch(void* const* d_in, const int* in_sizes, int n_in,
                              void* d_out, int out_size, void* d_ws, size_t ws_size,
                              hipStream_t stream) {
  (void)in_sizes; (void)n_in; (void)out_size; (void)ws_size;
  const float* x   = (const float*)d_in[0];
  const float* W_x = (const float*)d_in[1];
  const float* b_x = (const float*)d_in[2];
  const float* W_h = (const float*)d_in[3];
  const float* b_h = (const float*)d_in[4];
  const float* w_B = (const float*)d_in[5];
  const float* b_B = (const float*)d_in[6];
  float* out = (float*)d_out;

  char* ws = (char*)d_ws;
  unsigned short* Whh  = (unsigned short*)(ws + OFF_WHH);
  unsigned short* Wxh  = (unsigned short*)(ws + OFF_WXH);
  unsigned short* xhp  = (unsigned short*)(ws + OFF_XH);
  float*          bias = (float*)(ws + OFF_BIAS);
  unsigned short* hg   = (unsigned short*)(ws + OFF_HG);
  unsigned int*   flg  = (unsigned int*)(ws + OFF_FLG);

  static bool attr_done = false;
  // Setting an attribute is host-side (not a stream op) — safe under capture.
  hipFuncSetAttribute(reinterpret_cast<const void*>(lstm_persist),
                      hipFuncAttributeMaxDynamicSharedMemorySize, LDS_TOTAL);
  (void)attr_done;

  pack_w_kernel<<<dim3(6144), dim3(256), 0, stream>>>(W_h, W_x, Whh, Wxh);
  pack_x_kernel<<<dim3(4096), dim3(256), 0, stream>>>(x, xhp);
  prep_small_kernel<<<dim3(256), dim3(256), 0, stream>>>(b_x, b_h, w_B, b_B, bias, flg);
  lstm_persist<<<dim3(256), dim3(256), LDS_TOTAL, stream>>>(Whh, Wxh, xhp, bias, hg, flg, out);
}

// Round 5
// 1494.831 us; speedup vs baseline: 5.0265x; 3.3512x over previous
//
#include <hip/hip_runtime.h>
#include <hip/hip_cooperative_groups.h>

namespace cg = cooperative_groups;

// LSTM B=64 T=256 I=512 H=1024, fp32 in/out, fp16 MFMA compute (fp32 accum).
// Round 5: R3 structure + cooperative launch. Flags are zeroed INSIDE
// lstm_persist and published by grid.sync() before any use — immune to
// cross-replay stale values (the R4 post-timing divergence + tripwire cause).

using f32x4 = __attribute__((ext_vector_type(4))) float;
using u32x4 = __attribute__((ext_vector_type(4))) unsigned int;

#define NB 64
#define NT 256
#define NI 512
#define NH 1024

// ---- workspace layout (bytes) ----
#define OFF_WHH  0u
#define SZ_WHH   (4u*1024u*1024u*2u)        // fp16 [4 g][1024 u][1024 k]
#define OFF_WXH  (OFF_WHH + SZ_WHH)
#define SZ_WXH   (4u*1024u*512u*2u)         // fp16 [4 g][1024 u][512 k]
#define OFF_XH   (OFF_WXH + SZ_WXH)
#define SZ_XH    (256u*64u*512u*2u)         // fp16 [T][B][I]
#define OFF_BIAS (OFF_XH + SZ_XH)
#define SZ_BIAS  (4096u*4u)
#define OFF_HG   (OFF_BIAS + SZ_BIAS)
#define SZ_HG    (2u*4u*16u*1024u*2u)       // fp16 [2 buf][4 bt][16 b][1024 u]
#define OFF_FLG  (OFF_HG + SZ_HG)
#define SZ_FLG   (256u*4u*4u)               // u32 [T][4 bt] arrive-counters

// ---- LDS layout (bytes) ----
#define L_H    0        // 16 rows x 2048 B (fp16 [16 b][1024 k], XOR-swizzled)
#define L_WX   32768    // 64 rows x 1024 B (fp16 [g*16+u][512 k], XOR-swizzled)
#define L_ACC  98304    // fp32 [4 g][16 b][17] (stride-17 kills 4-way conflict)
#define L_HOUT 102656   // fp16 [16 b][16 u]
#define LDS_TOTAL 103168

__device__ __forceinline__ unsigned short f2h(float f) {
  _Float16 h = (_Float16)f;
  return __builtin_bit_cast(unsigned short, h);
}
__device__ __forceinline__ float sigmoid_f(float x) {
  return 1.0f / (1.0f + __expf(-x));
}
__device__ __forceinline__ float tanh_f(float x) {
  float xc = fminf(fmaxf(x, -15.0f), 15.0f);
  float e = __expf(2.0f * xc);
  return 1.0f - 2.0f / (e + 1.0f);
}

// ---------------- prep kernels ----------------

__global__ __launch_bounds__(256) void pack_w_kernel(
    const float* __restrict__ Wh, const float* __restrict__ Wx,
    unsigned short* __restrict__ WhP, unsigned short* __restrict__ WxP) {
  int base = (blockIdx.x * 256 + threadIdx.x) * 4;
  const int nWh = 4 * 1024 * 1024;
  const int nWx = 4 * 1024 * 512;
  if (base < nWh) {
    const float* s = Wh + base;
    unsigned int o0 = (unsigned int)f2h(s[0]) | ((unsigned int)f2h(s[1]) << 16);
    unsigned int o1 = (unsigned int)f2h(s[2]) | ((unsigned int)f2h(s[3]) << 16);
    ((unsigned int*)(WhP + base))[0] = o0;
    ((unsigned int*)(WhP + base))[1] = o1;
  } else {
    int b2 = base - nWh;
    if (b2 < nWx) {
      const float* s = Wx + b2;
      unsigned int o0 = (unsigned int)f2h(s[0]) | ((unsigned int)f2h(s[1]) << 16);
      unsigned int o1 = (unsigned int)f2h(s[2]) | ((unsigned int)f2h(s[3]) << 16);
      ((unsigned int*)(WxP + b2))[0] = o0;
      ((unsigned int*)(WxP + b2))[1] = o1;
    }
  }
}

// transpose x[B][T][I] fp32 -> xh[T][B][I] fp16
__global__ __launch_bounds__(256) void pack_x_kernel(
    const float* __restrict__ x, unsigned short* __restrict__ xh) {
  int gid = blockIdx.x * 256 + threadIdx.x;     // over B*T*(I/8) = 1,048,576
  int i8 = gid & 63;
  int t  = (gid >> 6) & 255;
  int b  = gid >> 14;
  const float* s = x + (((size_t)b * NT + t) * NI + i8 * 8);
  unsigned int w[4];
#pragma unroll
  for (int j = 0; j < 4; ++j)
    w[j] = (unsigned int)f2h(s[2*j]) | ((unsigned int)f2h(s[2*j+1]) << 16);
  u32x4 v = {w[0], w[1], w[2], w[3]};
  *(u32x4*)(xh + (((size_t)t * NB + b) * NI + i8 * 8)) = v;
}

__global__ __launch_bounds__(256) void prep_small_kernel(
    const float* __restrict__ b_x, const float* __restrict__ b_h,
    const float* __restrict__ w_B, const float* __restrict__ b_B,
    float* __restrict__ bias) {
  int gid = blockIdx.x * 256 + threadIdx.x;
  if (gid < 4096) bias[gid] = b_x[gid] + b_h[gid] + w_B[gid] + b_B[gid];
}

// ---------------- persistent LSTM kernel (cooperative) ----------------
// Block (bt, ug): 16 batches [bt*16..), 16 units [ug*16..), 4 gates.
// Wave g = gate g: one 16x16 MFMA tile, K = 512 (x, W_x in LDS) + 1024 (h,
// W_h in pinned VGPRs). MFMA 16x16x32 f16: A lane&15=row, lane>>4=k-chunk;
// B lane&15=col; D col=lane&15, row=(lane>>4)*4+reg.

__global__ __launch_bounds__(256, 1) void lstm_persist(
    const unsigned short* __restrict__ Whh,
    const unsigned short* __restrict__ Wxh,
    const unsigned short* __restrict__ xh,
    const float* __restrict__ bias,
    unsigned short* __restrict__ hglob,
    unsigned int* __restrict__ flags,
    float* __restrict__ out) {
  extern __shared__ char smem[];
  const int bid  = blockIdx.x;
  const int bt   = bid & 3;
  const int ug   = bid >> 2;
  const int tid  = threadIdx.x;
  const int g    = tid >> 6;        // wave index = gate
  const int lane = tid & 63;
  const int l15  = lane & 15;
  const int kg   = lane >> 4;

  cg::grid_group grid = cg::this_grid();

  // ---- zero this block's flag slots (visible after grid.sync) ----
  if (tid < 4)
    __hip_atomic_store(&flags[bid * 4 + tid], 0u,
                       __ATOMIC_RELAXED, __HIP_MEMORY_SCOPE_AGENT);

  // ---- W_h B-fragments into registers (once), PINNED ----
  u32x4 bh[32];
  {
    const unsigned short* wr = Whh + ((size_t)(g * 1024 + ug * 16 + l15)) * 1024 + kg * 8;
#pragma unroll
    for (int kc = 0; kc < 32; ++kc) bh[kc] = *(const u32x4*)(wr + kc * 32);
  }
#pragma unroll
  for (int kc = 0; kc < 32; ++kc)
    asm volatile("" : "+v"(bh[kc]));   // asm-defined: cannot be rematerialized
  // ---- W_x into LDS (once, swizzled) ----
  {
    int r = tid >> 2, seg = tid & 3;           // r = g'*16+u' (0..63)
    int gg = r >> 4, uu = r & 15;
    const unsigned short* wsrc = Wxh + ((size_t)(gg * 1024 + ug * 16 + uu)) * 512;
    char* row = smem + L_WX + r * 1024;
    int sw = (r & 7) << 4;
#pragma unroll
    for (int j = 0; j < 16; ++j) {
      int chunk = seg * 16 + j;                // 64 x 16B chunks per row
      u32x4 v = *(const u32x4*)(wsrc + chunk * 8);
      *(u32x4*)(row + ((chunk * 16) ^ sw)) = v;
    }
  }
  const float bv = bias[g * 1024 + ug * 16 + l15];
  __syncthreads();

  // ---- grid-wide barrier: flag zeros (and everything above) now visible ----
  grid.sync();

  const int eb = tid >> 4;   // epilogue batch-local
  const int eu = tid & 15;   // epilogue unit-local
  float c_reg = 0.0f;

  float* accl = (float*)(smem + L_ACC);
  unsigned short* houtl = (unsigned short*)(smem + L_HOUT);

  for (int t = 0; t < NT; ++t) {
    const int buf = t & 1, pbuf = buf ^ 1;

    f32x4 acc = {bv, bv, bv, bv};
    asm volatile("s_nop 1\ns_nop 1" ::);   // VALU -> MFMA srcC hazard guard

    // ---- x-part first (independent of h): K = 512, B-frags from LDS ----
    {
      const unsigned short* xp = xh + ((size_t)t * NB + bt * 16 + l15) * NI + kg * 8;
      const char* wxrow = smem + L_WX + (g * 16 + l15) * 1024;
      const int sw = (l15 & 7) << 4;
#pragma unroll
      for (int kc = 0; kc < 16; ++kc) {
        u32x4 a = *(const u32x4*)(xp + kc * 32);
        u32x4 b = *(const u32x4*)(wxrow + ((kc * 64 + kg * 16) ^ sw));
        asm("v_mfma_f32_16x16x32_f16 %0, %1, %2, %0" : "+v"(acc) : "v"(a), "v"(b));
      }
    }

    if (t > 0) {
      // ---- wave0 polls the (t-1,bt) arrive-counter (single broadcast line) ----
      if (g == 0) {
        const unsigned int* cp = flags + (t - 1) * 4 + bt;
        unsigned int fv;
        while (true) {
          asm volatile("global_load_dword %0, %1, off sc0 sc1\n\ts_waitcnt vmcnt(0)"
                       : "=v"(fv) : "v"(cp) : "memory");
          if (fv >= 64u) break;
          __builtin_amdgcn_s_sleep(2);
        }
      }
      __syncthreads();   // release stagers

      // ---- stage h(t-1) -> LDS (LLC-coherent loads, XOR-swizzled writes) ----
      const int sb = tid >> 4, sc = tid & 15;
      const unsigned short* hp = hglob + ((size_t)(pbuf * 4 + bt) * 16 + sb) * 1024 + sc * 8;
      u32x4 v0, v1, v2, v3, v4, v5, v6, v7;
      asm volatile(
          "global_load_dwordx4 %0, %[p], off sc0 sc1\n\t"
          "global_load_dwordx4 %1, %[p], off offset:256 sc0 sc1\n\t"
          "global_load_dwordx4 %2, %[p], off offset:512 sc0 sc1\n\t"
          "global_load_dwordx4 %3, %[p], off offset:768 sc0 sc1\n\t"
          "global_load_dwordx4 %4, %[p], off offset:1024 sc0 sc1\n\t"
          "global_load_dwordx4 %5, %[p], off offset:1280 sc0 sc1\n\t"
          "global_load_dwordx4 %6, %[p], off offset:1536 sc0 sc1\n\t"
          "global_load_dwordx4 %7, %[p], off offset:1792 sc0 sc1\n\t"
          "s_waitcnt vmcnt(0)"
          : "=&v"(v0), "=&v"(v1), "=&v"(v2), "=&v"(v3),
            "=&v"(v4), "=&v"(v5), "=&v"(v6), "=&v"(v7)
          : [p] "v"(hp)
          : "memory");
      char* hrow = smem + L_H + sb * 2048;
      const int sw = (sb & 7) << 4;
      *(u32x4*)(hrow + ((sc * 16 +    0) ^ sw)) = v0;
      *(u32x4*)(hrow + ((sc * 16 +  256) ^ sw)) = v1;
      *(u32x4*)(hrow + ((sc * 16 +  512) ^ sw)) = v2;
      *(u32x4*)(hrow + ((sc * 16 +  768) ^ sw)) = v3;
      *(u32x4*)(hrow + ((sc * 16 + 1024) ^ sw)) = v4;
      *(u32x4*)(hrow + ((sc * 16 + 1280) ^ sw)) = v5;
      *(u32x4*)(hrow + ((sc * 16 + 1536) ^ sw)) = v6;
      *(u32x4*)(hrow + ((sc * 16 + 1792) ^ sw)) = v7;
      __syncthreads();

      // ---- h-part: K = 1024, B-frags from pinned registers ----
      const char* hbase = smem + L_H + l15 * 2048;
      const int swh = (l15 & 7) << 4;
#pragma unroll
      for (int kc = 0; kc < 32; ++kc) {
        u32x4 a = *(const u32x4*)(hbase + ((kc * 64 + kg * 16) ^ swh));
        asm("v_mfma_f32_16x16x32_f16 %0, %1, %2, %0" : "+v"(acc) : "v"(a), "v"(bh[kc]));
      }
    }
    asm volatile("s_nop 7\ns_nop 7\ns_nop 7" ::);  // MFMA -> VALU hazard guard

    // ---- gate exchange through LDS: accl[g][b][17] ----
#pragma unroll
    for (int r = 0; r < 4; ++r)
      accl[g * 272 + (kg * 4 + r) * 17 + l15] = acc[r];
    __syncthreads();

    // ---- pointwise epilogue: thread -> (eb, eu) ----
    {
      float gf = accl[0 * 272 + eb * 17 + eu];
      float gi = accl[1 * 272 + eb * 17 + eu];
      float gc = accl[2 * 272 + eb * 17 + eu];
      float go = accl[3 * 272 + eb * 17 + eu];
      float f  = sigmoid_f(gf);
      float i  = sigmoid_f(gi);
      float cb = tanh_f(gc);
      float o  = sigmoid_f(go);
      float cn = f * c_reg + i * cb;
      c_reg = cn;
      float hn = o * tanh_f(cn);
      out[(((size_t)(bt * 16 + eb)) * NT + t) * NH + ug * 16 + eu] = hn;
      houtl[eb * 16 + eu] = f2h(hn);
    }
    __syncthreads();

    // ---- publish h(t) slice (LLC-coherent) + arrive ----
    if (t + 1 < NT) {
      if (tid < 32) {
        u32x4 hv = *(const u32x4*)(houtl + tid * 8);   // 8 fp16 = 16 B
        unsigned short* dst = hglob + ((size_t)(buf * 4 + bt) * 16 + (tid >> 1)) * 1024
                            + ug * 16 + (tid & 1) * 8;
        asm volatile("global_store_dwordx4 %[p], %[v], off sc0 sc1\n\t"
                     "s_waitcnt vmcnt(0)"
                     :: [p] "v"(dst), [v] "v"(hv) : "memory");
      }
      if (tid == 0)
        __hip_atomic_fetch_add(&flags[t * 4 + bt], 1u,
                               __ATOMIC_RELAXED, __HIP_MEMORY_SCOPE_AGENT);
    }
  }
}

// ---------------- host launcher ----------------

extern "C" void kernel_launch(void* const* d_in, const int* in_sizes, int n_in,
                              void* d_out, int out_size, void* d_ws, size_t ws_size,
                              hipStream_t stream) {
  (void)in_sizes; (void)n_in; (void)out_size; (void)ws_size;
  const float* x   = (const float*)d_in[0];
  const float* W_x = (const float*)d_in[1];
  const float* b_x = (const float*)d_in[2];
  const float* W_h = (const float*)d_in[3];
  const float* b_h = (const float*)d_in[4];
  const float* w_B = (const float*)d_in[5];
  const float* b_B = (const float*)d_in[6];
  float* out = (float*)d_out;

  char* ws = (char*)d_ws;
  unsigned short* Whh  = (unsigned short*)(ws + OFF_WHH);
  unsigned short* Wxh  = (unsigned short*)(ws + OFF_WXH);
  unsigned short* xhp  = (unsigned short*)(ws + OFF_XH);
  float*          bias = (float*)(ws + OFF_BIAS);
  unsigned short* hg   = (unsigned short*)(ws + OFF_HG);
  unsigned int*   flg  = (unsigned int*)(ws + OFF_FLG);

  hipFuncSetAttribute(reinterpret_cast<const void*>(lstm_persist),
                      hipFuncAttributeMaxDynamicSharedMemorySize, LDS_TOTAL);

  pack_w_kernel<<<dim3(6144), dim3(256), 0, stream>>>(W_h, W_x, Whh, Wxh);
  pack_x_kernel<<<dim3(4096), dim3(256), 0, stream>>>(x, xhp);
  prep_small_kernel<<<dim3(16), dim3(256), 0, stream>>>(b_x, b_h, w_B, b_B, bias);

  void* kargs[] = {(void*)&Whh, (void*)&Wxh, (void*)&xhp, (void*)&bias,
                   (void*)&hg, (void*)&flg, (void*)&out};
  hipLaunchCooperativeKernel(reinterpret_cast<void*>(lstm_persist),
                             dim3(256), dim3(256), kargs, LDS_TOTAL, stream);
}

// Round 9
// 1478.732 us; speedup vs baseline: 5.0813x; 1.0109x over previous
//
#include <hip/hip_runtime.h>
#include <hip/hip_cooperative_groups.h>

namespace cg = cooperative_groups;

// LSTM B=64 T=256 I=512 H=1024, fp32 in/out, fp16 MFMA compute (fp32 accum).
// Round 9: EXACT R5 body (single acc chain, validated asm shapes). ONE delta:
// per-producer flag words (sc0/sc1 store of 1) + 64-lane parallel poll,
// replacing the 64-RMW serialized atomicAdd fan-in on a single LLC line.

using f32x4 = __attribute__((ext_vector_type(4))) float;
using u32x4 = __attribute__((ext_vector_type(4))) unsigned int;

#define NB 64
#define NT 256
#define NI 512
#define NH 1024

// ---- workspace layout (bytes) ----
#define OFF_WHH  0u
#define SZ_WHH   (4u*1024u*1024u*2u)        // fp16 [4 g][1024 u][1024 k]
#define OFF_WXH  (OFF_WHH + SZ_WHH)
#define SZ_WXH   (4u*1024u*512u*2u)         // fp16 [4 g][1024 u][512 k]
#define OFF_XH   (OFF_WXH + SZ_WXH)
#define SZ_XH    (256u*64u*512u*2u)         // fp16 [T][B][I]
#define OFF_BIAS (OFF_XH + SZ_XH)
#define SZ_BIAS  (4096u*4u)
#define OFF_HG   (OFF_BIAS + SZ_BIAS)
#define SZ_HG    (2u*4u*16u*1024u*2u)       // fp16 [2 buf][4 bt][16 b][1024 u]
#define OFF_FLG  (OFF_HG + SZ_HG)
#define SZ_FLG   (256u*4u*64u*4u)           // u32 [T][4 bt][64 ug] per-producer

// ---- LDS layout (bytes) ----
#define L_H    0        // 16 rows x 2048 B (fp16 [16 b][1024 k], XOR-swizzled)
#define L_WX   32768    // 64 rows x 1024 B (fp16 [g*16+u][512 k], XOR-swizzled)
#define L_ACC  98304    // fp32 [4 g][16 b][17] (stride-17 kills 4-way conflict)
#define L_HOUT 102656   // fp16 [16 b][16 u]
#define LDS_TOTAL 103168

__device__ __forceinline__ unsigned short f2h(float f) {
  _Float16 h = (_Float16)f;
  return __builtin_bit_cast(unsigned short, h);
}
__device__ __forceinline__ float sigmoid_f(float x) {
  return 1.0f / (1.0f + __expf(-x));
}
__device__ __forceinline__ float tanh_f(float x) {
  float xc = fminf(fmaxf(x, -15.0f), 15.0f);
  float e = __expf(2.0f * xc);
  return 1.0f - 2.0f / (e + 1.0f);
}

// ---------------- prep kernels ----------------

__global__ __launch_bounds__(256) void pack_w_kernel(
    const float* __restrict__ Wh, const float* __restrict__ Wx,
    unsigned short* __restrict__ WhP, unsigned short* __restrict__ WxP) {
  int base = (blockIdx.x * 256 + threadIdx.x) * 4;
  const int nWh = 4 * 1024 * 1024;
  const int nWx = 4 * 1024 * 512;
  if (base < nWh) {
    const float* s = Wh + base;
    unsigned int o0 = (unsigned int)f2h(s[0]) | ((unsigned int)f2h(s[1]) << 16);
    unsigned int o1 = (unsigned int)f2h(s[2]) | ((unsigned int)f2h(s[3]) << 16);
    ((unsigned int*)(WhP + base))[0] = o0;
    ((unsigned int*)(WhP + base))[1] = o1;
  } else {
    int b2 = base - nWh;
    if (b2 < nWx) {
      const float* s = Wx + b2;
      unsigned int o0 = (unsigned int)f2h(s[0]) | ((unsigned int)f2h(s[1]) << 16);
      unsigned int o1 = (unsigned int)f2h(s[2]) | ((unsigned int)f2h(s[3]) << 16);
      ((unsigned int*)(WxP + b2))[0] = o0;
      ((unsigned int*)(WxP + b2))[1] = o1;
    }
  }
}

// transpose x[B][T][I] fp32 -> xh[T][B][I] fp16
__global__ __launch_bounds__(256) void pack_x_kernel(
    const float* __restrict__ x, unsigned short* __restrict__ xh) {
  int gid = blockIdx.x * 256 + threadIdx.x;     // over B*T*(I/8) = 1,048,576
  int i8 = gid & 63;
  int t  = (gid >> 6) & 255;
  int b  = gid >> 14;
  const float* s = x + (((size_t)b * NT + t) * NI + i8 * 8);
  unsigned int w[4];
#pragma unroll
  for (int j = 0; j < 4; ++j)
    w[j] = (unsigned int)f2h(s[2*j]) | ((unsigned int)f2h(s[2*j+1]) << 16);
  u32x4 v = {w[0], w[1], w[2], w[3]};
  *(u32x4*)(xh + (((size_t)t * NB + b) * NI + i8 * 8)) = v;
}

__global__ __launch_bounds__(256) void prep_small_kernel(
    const float* __restrict__ b_x, const float* __restrict__ b_h,
    const float* __restrict__ w_B, const float* __restrict__ b_B,
    float* __restrict__ bias) {
  int gid = blockIdx.x * 256 + threadIdx.x;
  if (gid < 4096) bias[gid] = b_x[gid] + b_h[gid] + w_B[gid] + b_B[gid];
}

// ---------------- persistent LSTM kernel (cooperative) ----------------
// Block (bt, ug): 16 batches [bt*16..), 16 units [ug*16..), 4 gates.
// Wave g = gate g: one 16x16 MFMA tile, K = 512 (x, W_x in LDS) + 1024 (h,
// W_h in pinned VGPRs). MFMA 16x16x32 f16: A lane&15=row, lane>>4=k-chunk;
// B lane&15=col; D col=lane&15, row=(lane>>4)*4+reg.

__global__ __launch_bounds__(256, 1) void lstm_persist(
    const unsigned short* __restrict__ Whh,
    const unsigned short* __restrict__ Wxh,
    const unsigned short* __restrict__ xh,
    const float* __restrict__ bias,
    unsigned short* __restrict__ hglob,
    unsigned int* __restrict__ flags,
    float* __restrict__ out) {
  extern __shared__ char smem[];
  const int bid  = blockIdx.x;
  const int bt   = bid & 3;
  const int ug   = bid >> 2;
  const int tid  = threadIdx.x;
  const int g    = tid >> 6;        // wave index = gate
  const int lane = tid & 63;
  const int l15  = lane & 15;
  const int kg   = lane >> 4;

  cg::grid_group grid = cg::this_grid();

  // ---- zero this block's 256 flag words (visible after grid.sync) ----
  __hip_atomic_store(&flags[bid * 256 + tid], 0u,
                     __ATOMIC_RELAXED, __HIP_MEMORY_SCOPE_AGENT);

  // ---- W_h B-fragments into registers (once), pinned (R5-validated) ----
  u32x4 bh[32];
  {
    const unsigned short* wr = Whh + ((size_t)(g * 1024 + ug * 16 + l15)) * 1024 + kg * 8;
#pragma unroll
    for (int kc = 0; kc < 32; ++kc) bh[kc] = *(const u32x4*)(wr + kc * 32);
  }
#pragma unroll
  for (int kc = 0; kc < 32; ++kc)
    asm volatile("" : "+v"(bh[kc]));
  // ---- W_x into LDS (once, swizzled) ----
  {
    int r = tid >> 2, seg = tid & 3;           // r = g'*16+u' (0..63)
    int gg = r >> 4, uu = r & 15;
    const unsigned short* wsrc = Wxh + ((size_t)(gg * 1024 + ug * 16 + uu)) * 512;
    char* row = smem + L_WX + r * 1024;
    int sw = (r & 7) << 4;
#pragma unroll
    for (int j = 0; j < 16; ++j) {
      int chunk = seg * 16 + j;                // 64 x 16B chunks per row
      u32x4 v = *(const u32x4*)(wsrc + chunk * 8);
      *(u32x4*)(row + ((chunk * 16) ^ sw)) = v;
    }
  }
  const float bv = bias[g * 1024 + ug * 16 + l15];
  __syncthreads();

  // ---- grid-wide barrier: flag zeros (and everything above) now visible ----
  grid.sync();

  const int eb = tid >> 4;   // epilogue batch-local
  const int eu = tid & 15;   // epilogue unit-local
  float c_reg = 0.0f;

  float* accl = (float*)(smem + L_ACC);
  unsigned short* houtl = (unsigned short*)(smem + L_HOUT);

  for (int t = 0; t < NT; ++t) {
    const int buf = t & 1, pbuf = buf ^ 1;

    f32x4 acc = {bv, bv, bv, bv};
    asm volatile("s_nop 1\ns_nop 1" ::);   // VALU -> MFMA srcC hazard guard

    // ---- x-part first (independent of h): K = 512, B-frags from LDS ----
    {
      const unsigned short* xp = xh + ((size_t)t * NB + bt * 16 + l15) * NI + kg * 8;
      const char* wxrow = smem + L_WX + (g * 16 + l15) * 1024;
      const int sw = (l15 & 7) << 4;
#pragma unroll
      for (int kc = 0; kc < 16; ++kc) {
        u32x4 a = *(const u32x4*)(xp + kc * 32);
        u32x4 b = *(const u32x4*)(wxrow + ((kc * 64 + kg * 16) ^ sw));
        asm("v_mfma_f32_16x16x32_f16 %0, %1, %2, %0" : "+v"(acc) : "v"(a), "v"(b));
      }
    }

    if (t > 0) {
      // ---- wave0: 64-lane parallel poll of per-producer flag words ----
      if (g == 0) {
        const unsigned int* cp = flags + ((t - 1) * 4 + bt) * 64 + lane;
        unsigned int fv;
        while (true) {
          asm volatile("global_load_dword %0, %1, off sc0 sc1\n\ts_waitcnt vmcnt(0)"
                       : "=v"(fv) : "v"(cp) : "memory");
          if (__all(fv == 1u)) break;
          __builtin_amdgcn_s_sleep(2);
        }
      }
      __syncthreads();   // release stagers

      // ---- stage h(t-1) -> LDS (LLC-coherent loads, XOR-swizzled writes) ----
      const int sb = tid >> 4, sc = tid & 15;
      const unsigned short* hp = hglob + ((size_t)(pbuf * 4 + bt) * 16 + sb) * 1024 + sc * 8;
      u32x4 v0, v1, v2, v3, v4, v5, v6, v7;
      asm volatile(
          "global_load_dwordx4 %0, %[p], off sc0 sc1\n\t"
          "global_load_dwordx4 %1, %[p], off offset:256 sc0 sc1\n\t"
          "global_load_dwordx4 %2, %[p], off offset:512 sc0 sc1\n\t"
          "global_load_dwordx4 %3, %[p], off offset:768 sc0 sc1\n\t"
          "global_load_dwordx4 %4, %[p], off offset:1024 sc0 sc1\n\t"
          "global_load_dwordx4 %5, %[p], off offset:1280 sc0 sc1\n\t"
          "global_load_dwordx4 %6, %[p], off offset:1536 sc0 sc1\n\t"
          "global_load_dwordx4 %7, %[p], off offset:1792 sc0 sc1\n\t"
          "s_waitcnt vmcnt(0)"
          : "=&v"(v0), "=&v"(v1), "=&v"(v2), "=&v"(v3),
            "=&v"(v4), "=&v"(v5), "=&v"(v6), "=&v"(v7)
          : [p] "v"(hp)
          : "memory");
      char* hrow = smem + L_H + sb * 2048;
      const int sw = (sb & 7) << 4;
      *(u32x4*)(hrow + ((sc * 16 +    0) ^ sw)) = v0;
      *(u32x4*)(hrow + ((sc * 16 +  256) ^ sw)) = v1;
      *(u32x4*)(hrow + ((sc * 16 +  512) ^ sw)) = v2;
      *(u32x4*)(hrow + ((sc * 16 +  768) ^ sw)) = v3;
      *(u32x4*)(hrow + ((sc * 16 + 1024) ^ sw)) = v4;
      *(u32x4*)(hrow + ((sc * 16 + 1280) ^ sw)) = v5;
      *(u32x4*)(hrow + ((sc * 16 + 1536) ^ sw)) = v6;
      *(u32x4*)(hrow + ((sc * 16 + 1792) ^ sw)) = v7;
      __syncthreads();

      // ---- h-part: K = 1024, B-frags from pinned registers ----
      const char* hbase = smem + L_H + l15 * 2048;
      const int swh = (l15 & 7) << 4;
#pragma unroll
      for (int kc = 0; kc < 32; ++kc) {
        u32x4 a = *(const u32x4*)(hbase + ((kc * 64 + kg * 16) ^ swh));
        asm("v_mfma_f32_16x16x32_f16 %0, %1, %2, %0" : "+v"(acc) : "v"(a), "v"(bh[kc]));
      }
    }
    asm volatile("s_nop 7\ns_nop 7\ns_nop 7" ::);  // MFMA -> VALU hazard guard

    // ---- gate exchange through LDS: accl[g][b][17] ----
#pragma unroll
    for (int r = 0; r < 4; ++r)
      accl[g * 272 + (kg * 4 + r) * 17 + l15] = acc[r];
    __syncthreads();

    // ---- pointwise epilogue: thread -> (eb, eu) ----
    {
      float gf = accl[0 * 272 + eb * 17 + eu];
      float gi = accl[1 * 272 + eb * 17 + eu];
      float gc = accl[2 * 272 + eb * 17 + eu];
      float go = accl[3 * 272 + eb * 17 + eu];
      float f  = sigmoid_f(gf);
      float i  = sigmoid_f(gi);
      float cb = tanh_f(gc);
      float o  = sigmoid_f(go);
      float cn = f * c_reg + i * cb;
      c_reg = cn;
      float hn = o * tanh_f(cn);
      out[(((size_t)(bt * 16 + eb)) * NT + t) * NH + ug * 16 + eu] = hn;
      houtl[eb * 16 + eu] = f2h(hn);
    }
    __syncthreads();

    // ---- publish h(t) slice (LLC-coherent) + per-producer flag ----
    if (t + 1 < NT) {
      if (tid < 32) {
        u32x4 hv = *(const u32x4*)(houtl + tid * 8);   // 8 fp16 = 16 B
        unsigned short* dst = hglob + ((size_t)(buf * 4 + bt) * 16 + (tid >> 1)) * 1024
                            + ug * 16 + (tid & 1) * 8;
        asm volatile("global_store_dwordx4 %[p], %[v], off sc0 sc1\n\t"
                     "s_waitcnt vmcnt(0)"
                     :: [p] "v"(dst), [v] "v"(hv) : "memory");
      }
      // same wave (wave0), program-ordered after the publish vmcnt(0)
      if (tid == 0) {
        unsigned int* fp = flags + (t * 4 + bt) * 64 + ug;
        unsigned int one = 1u;
        asm volatile("global_store_dword %0, %1, off sc0 sc1"
                     :: "v"(fp), "v"(one) : "memory");
      }
    }
  }
}

// ---------------- host launcher ----------------

extern "C" void kernel_launch(void* const* d_in, const int* in_sizes, int n_in,
                              void* d_out, int out_size, void* d_ws, size_t ws_size,
                              hipStream_t stream) {
  (void)in_sizes; (void)n_in; (void)out_size; (void)ws_size;
  const float* x   = (const float*)d_in[0];
  const float* W_x = (const float*)d_in[1];
  const float* b_x = (const float*)d_in[2];
  const float* W_h = (const float*)d_in[3];
  const float* b_h = (const float*)d_in[4];
  const float* w_B = (const float*)d_in[5];
  const float* b_B = (const float*)d_in[6];
  float* out = (float*)d_out;

  char* ws = (char*)d_ws;
  unsigned short* Whh  = (unsigned short*)(ws + OFF_WHH);
  unsigned short* Wxh  = (unsigned short*)(ws + OFF_WXH);
  unsigned short* xhp  = (unsigned short*)(ws + OFF_XH);
  float*          bias = (float*)(ws + OFF_BIAS);
  unsigned short* hg   = (unsigned short*)(ws + OFF_HG);
  unsigned int*   flg  = (unsigned int*)(ws + OFF_FLG);

  hipFuncSetAttribute(reinterpret_cast<const void*>(lstm_persist),
                      hipFuncAttributeMaxDynamicSharedMemorySize, LDS_TOTAL);

  pack_w_kernel<<<dim3(6144), dim3(256), 0, stream>>>(W_h, W_x, Whh, Wxh);
  pack_x_kernel<<<dim3(4096), dim3(256), 0, stream>>>(x, xhp);
  prep_small_kernel<<<dim3(16), dim3(256), 0, stream>>>(b_x, b_h, w_B, b_B, bias);

  void* kargs[] = {(void*)&Whh, (void*)&Wxh, (void*)&xhp, (void*)&bias,
                   (void*)&hg, (void*)&flg, (void*)&out};
  hipLaunchCooperativeKernel(reinterpret_cast<void*>(lstm_persist),
                             dim3(256), dim3(256), kargs, LDS_TOTAL, stream);
}

// Round 15
// 1383.828 us; speedup vs baseline: 5.4297x; 1.0686x over previous
//
#include <hip/hip_runtime.h>
#include <hip/hip_cooperative_groups.h>

namespace cg = cooperative_groups;

// LSTM B=64 T=256 I=512 H=1024, fp32 in/out, fp16 MFMA compute (fp32 accum).
// Round 15: R14 architecture + DATAFLOW-CARRIED hazard guards.
//   The old pattern (plain s_nop asm next to non-volatile MFMA asm) only
//   worked by scheduling luck: plain init-movs and MFMAs can both drift
//   across independent volatile asm. New guards embed the s_nops in an asm
//   that reads+writes acc, so ordering is forced by dataflow:
//     init movs -> [s_nops "+v"(acc)] -> MFMAs -> [s_nops "+v"(acc)] -> VALU.
//   Applied to xg_gemm and both persistent kernels.

using f32x4 = __attribute__((ext_vector_type(4))) float;
using u32x4 = __attribute__((ext_vector_type(4))) unsigned int;

#define NB 64
#define NT 256
#define NI 512
#define NH 1024

// ---- workspace layout (bytes) ----
#define OFF_WHH  0u
#define SZ_WHH   (4u*1024u*1024u*2u)        // fp16 [4 g][1024 u][1024 k]
#define OFF_WXH  (OFF_WHH + SZ_WHH)
#define SZ_WXH   (4u*1024u*512u*2u)         // fp16 [4 g][1024 u][512 k]
#define OFF_XH   (OFF_WXH + SZ_WXH)
#define SZ_XH    (256u*64u*512u*2u)         // fp16 [T][B][I]
#define OFF_BIAS (OFF_XH + SZ_XH)
#define SZ_BIAS  (4096u*4u)
#define OFF_HG   (OFF_BIAS + SZ_BIAS)
#define SZ_HG    (2u*4u*16u*1024u*2u)       // fp16 [2 buf][4 bt][16 b][1024 u]
#define OFF_FLG  (OFF_HG + SZ_HG)
#define SZ_FLG   (256u*4u*64u*4u)           // u32 [T][4 bt][64 ug] per-producer
#define OFF_XG   (OFF_FLG + SZ_FLG)
#define SZ_XG    (256ull*64ull*4ull*1024ull*2ull)  // fp16 [T][B][4 g][1024 u]

// ---- LDS layouts (bytes) ----
#define L_H    0        // 16 rows x 2048 B (fp16 [16 b][1024 k], XOR-swizzled)
#define L_WX   32768    // (slow path) 64 rows x 1024 B swizzled W_x
#define L_ACC_S  98304  // slow path: fp32 [4 g][16 b][17]
#define L_HOUT_S 102656
#define LDS_SLOW 103168
#define L_ACC_F  32768  // fast path: fp32 [4 g][16 b][17]
#define L_HOUT_F 37120
#define LDS_FAST 37632
#define XG_LDS   65536

// dataflow-carried hazard guards (see header comment)
#define GUARD_PRE(acc)  asm volatile("s_nop 1\ns_nop 1" : "+v"(acc))
#define GUARD_POST(acc) asm volatile("s_nop 7\ns_nop 7\ns_nop 7" : "+v"(acc))

__device__ __forceinline__ unsigned short f2h(float f) {
  _Float16 h = (_Float16)f;
  return __builtin_bit_cast(unsigned short, h);
}
__device__ __forceinline__ float h2f(unsigned short u) {
  _Float16 h = __builtin_bit_cast(_Float16, u);
  return (float)h;
}
__device__ __forceinline__ float sigmoid_f(float x) {
  return 1.0f / (1.0f + __expf(-x));
}
__device__ __forceinline__ float tanh_f(float x) {
  float xc = fminf(fmaxf(x, -15.0f), 15.0f);
  float e = __expf(2.0f * xc);
  return 1.0f - 2.0f / (e + 1.0f);
}

// ---------------- prep kernels ----------------

__global__ __launch_bounds__(256) void pack_w_kernel(
    const float* __restrict__ Wh, const float* __restrict__ Wx,
    unsigned short* __restrict__ WhP, unsigned short* __restrict__ WxP) {
  int base = (blockIdx.x * 256 + threadIdx.x) * 4;
  const int nWh = 4 * 1024 * 1024;
  const int nWx = 4 * 1024 * 512;
  if (base < nWh) {
    const float* s = Wh + base;
    unsigned int o0 = (unsigned int)f2h(s[0]) | ((unsigned int)f2h(s[1]) << 16);
    unsigned int o1 = (unsigned int)f2h(s[2]) | ((unsigned int)f2h(s[3]) << 16);
    ((unsigned int*)(WhP + base))[0] = o0;
    ((unsigned int*)(WhP + base))[1] = o1;
  } else {
    int b2 = base - nWh;
    if (b2 < nWx) {
      const float* s = Wx + b2;
      unsigned int o0 = (unsigned int)f2h(s[0]) | ((unsigned int)f2h(s[1]) << 16);
      unsigned int o1 = (unsigned int)f2h(s[2]) | ((unsigned int)f2h(s[3]) << 16);
      ((unsigned int*)(WxP + b2))[0] = o0;
      ((unsigned int*)(WxP + b2))[1] = o1;
    }
  }
}

// transpose x[B][T][I] fp32 -> xh[T][B][I] fp16
__global__ __launch_bounds__(256) void pack_x_kernel(
    const float* __restrict__ x, unsigned short* __restrict__ xh) {
  int gid = blockIdx.x * 256 + threadIdx.x;     // over B*T*(I/8) = 1,048,576
  int i8 = gid & 63;
  int t  = (gid >> 6) & 255;
  int b  = gid >> 14;
  const float* s = x + (((size_t)b * NT + t) * NI + i8 * 8);
  unsigned int w[4];
#pragma unroll
  for (int j = 0; j < 4; ++j)
    w[j] = (unsigned int)f2h(s[2*j]) | ((unsigned int)f2h(s[2*j+1]) << 16);
  u32x4 v = {w[0], w[1], w[2], w[3]};
  *(u32x4*)(xh + (((size_t)t * NB + b) * NI + i8 * 8)) = v;
}

__global__ __launch_bounds__(256) void prep_small_kernel(
    const float* __restrict__ b_x, const float* __restrict__ b_h,
    const float* __restrict__ w_B, const float* __restrict__ b_B,
    float* __restrict__ bias) {
  int gid = blockIdx.x * 256 + threadIdx.x;
  if (gid < 4096) bias[gid] = b_x[gid] + b_h[gid] + w_B[gid] + b_B[gid];
}

// ---------------- xg precompute GEMM (fast path only) ----------
// xg[t][b][g][u] = sum_k xh[t][b][k] * Wx[g*1024+u][k]   (fp16 out)

__global__ __launch_bounds__(256) void xg_gemm(
    const unsigned short* __restrict__ Wxh,
    const unsigned short* __restrict__ xh,
    unsigned short* __restrict__ xg) {
  extern __shared__ char smem[];
  const int ug     = blockIdx.x & 63;
  const int mchunk = blockIdx.x >> 6;
  const int tid  = threadIdx.x;
  const int g    = tid >> 6;
  const int l15  = tid & 15;
  const int kg   = (tid & 63) >> 4;

  {
    int r = tid >> 2, seg = tid & 3;
    int gg = r >> 4, uu = r & 15;
    const unsigned short* wsrc = Wxh + ((size_t)(gg * 1024 + ug * 16 + uu)) * 512;
    char* row = smem + r * 1024;
    int sw = (r & 7) << 4;
#pragma unroll
    for (int j = 0; j < 16; ++j) {
      int chunk = seg * 16 + j;
      u32x4 v = *(const u32x4*)(wsrc + chunk * 8);
      *(u32x4*)(row + ((chunk * 16) ^ sw)) = v;
    }
  }
  __syncthreads();

  const char* wxrow = smem + (g * 16 + l15) * 1024;
  const int swl = (l15 & 7) << 4;

  for (int mt = mchunk * 64; mt < mchunk * 64 + 64; ++mt) {
    const int t  = mt >> 2;
    const int b0 = (mt & 3) << 4;

    f32x4 acc = {0.0f, 0.0f, 0.0f, 0.0f};
    GUARD_PRE(acc);   // movs -> nops -> MFMAs, enforced by dataflow

    const unsigned short* xp = xh + ((size_t)t * NB + b0 + l15) * NI + kg * 8;
#pragma unroll
    for (int kc = 0; kc < 16; ++kc) {
      u32x4 a = *(const u32x4*)(xp + kc * 32);
      u32x4 b = *(const u32x4*)(wxrow + ((kc * 64 + kg * 16) ^ swl));
      asm("v_mfma_f32_16x16x32_f16 %0, %1, %2, %0" : "+v"(acc) : "v"(a), "v"(b));
    }
    GUARD_POST(acc);  // MFMAs -> nops -> VALU reads, enforced by dataflow

#pragma unroll
    for (int r = 0; r < 4; ++r) {
      size_t addr = (((size_t)t * NB + b0 + kg * 4 + r) * 4 + g) * 1024 + ug * 16 + l15;
      xg[addr] = f2h(acc[r]);
    }
  }
}

// ---------------- persistent LSTM kernel: SLOW path (R9 + robust guards) ---

__global__ __launch_bounds__(256, 1) void lstm_persist_slow(
    const unsigned short* __restrict__ Whh,
    const unsigned short* __restrict__ Wxh,
    const unsigned short* __restrict__ xh,
    const float* __restrict__ bias,
    unsigned short* __restrict__ hglob,
    unsigned int* __restrict__ flags,
    float* __restrict__ out) {
  extern __shared__ char smem[];
  const int bid  = blockIdx.x;
  const int bt   = bid & 3;
  const int ug   = bid >> 2;
  const int tid  = threadIdx.x;
  const int g    = tid >> 6;
  const int lane = tid & 63;
  const int l15  = lane & 15;
  const int kg   = lane >> 4;

  cg::grid_group grid = cg::this_grid();

  __hip_atomic_store(&flags[bid * 256 + tid], 0u,
                     __ATOMIC_RELAXED, __HIP_MEMORY_SCOPE_AGENT);

  u32x4 bh[32];
  {
    const unsigned short* wr = Whh + ((size_t)(g * 1024 + ug * 16 + l15)) * 1024 + kg * 8;
#pragma unroll
    for (int kc = 0; kc < 32; ++kc) bh[kc] = *(const u32x4*)(wr + kc * 32);
  }
#pragma unroll
  for (int kc = 0; kc < 32; ++kc)
    asm volatile("" : "+v"(bh[kc]));
  {
    int r = tid >> 2, seg = tid & 3;
    int gg = r >> 4, uu = r & 15;
    const unsigned short* wsrc = Wxh + ((size_t)(gg * 1024 + ug * 16 + uu)) * 512;
    char* row = smem + L_WX + r * 1024;
    int sw = (r & 7) << 4;
#pragma unroll
    for (int j = 0; j < 16; ++j) {
      int chunk = seg * 16 + j;
      u32x4 v = *(const u32x4*)(wsrc + chunk * 8);
      *(u32x4*)(row + ((chunk * 16) ^ sw)) = v;
    }
  }
  const float bv = bias[g * 1024 + ug * 16 + l15];
  __syncthreads();

  grid.sync();

  const int eb = tid >> 4;
  const int eu = tid & 15;
  float c_reg = 0.0f;

  float* accl = (float*)(smem + L_ACC_S);
  unsigned short* houtl = (unsigned short*)(smem + L_HOUT_S);

  for (int t = 0; t < NT; ++t) {
    const int buf = t & 1, pbuf = buf ^ 1;

    f32x4 acc = {bv, bv, bv, bv};
    GUARD_PRE(acc);

    {
      const unsigned short* xp = xh + ((size_t)t * NB + bt * 16 + l15) * NI + kg * 8;
      const char* wxrow = smem + L_WX + (g * 16 + l15) * 1024;
      const int sw = (l15 & 7) << 4;
#pragma unroll
      for (int kc = 0; kc < 16; ++kc) {
        u32x4 a = *(const u32x4*)(xp + kc * 32);
        u32x4 b = *(const u32x4*)(wxrow + ((kc * 64 + kg * 16) ^ sw));
        asm("v_mfma_f32_16x16x32_f16 %0, %1, %2, %0" : "+v"(acc) : "v"(a), "v"(b));
      }
    }

    if (t > 0) {
      if (g == 0) {
        const unsigned int* cp = flags + ((t - 1) * 4 + bt) * 64 + lane;
        unsigned int fv;
        while (true) {
          asm volatile("global_load_dword %0, %1, off sc0 sc1\n\ts_waitcnt vmcnt(0)"
                       : "=v"(fv) : "v"(cp) : "memory");
          if (__all(fv == 1u)) break;
          __builtin_amdgcn_s_sleep(2);
        }
      }
      __syncthreads();

      const int sb = tid >> 4, sc = tid & 15;
      const unsigned short* hp = hglob + ((size_t)(pbuf * 4 + bt) * 16 + sb) * 1024 + sc * 8;
      u32x4 v0, v1, v2, v3, v4, v5, v6, v7;
      asm volatile(
          "global_load_dwordx4 %0, %[p], off sc0 sc1\n\t"
          "global_load_dwordx4 %1, %[p], off offset:256 sc0 sc1\n\t"
          "global_load_dwordx4 %2, %[p], off offset:512 sc0 sc1\n\t"
          "global_load_dwordx4 %3, %[p], off offset:768 sc0 sc1\n\t"
          "global_load_dwordx4 %4, %[p], off offset:1024 sc0 sc1\n\t"
          "global_load_dwordx4 %5, %[p], off offset:1280 sc0 sc1\n\t"
          "global_load_dwordx4 %6, %[p], off offset:1536 sc0 sc1\n\t"
          "global_load_dwordx4 %7, %[p], off offset:1792 sc0 sc1\n\t"
          "s_waitcnt vmcnt(0)"
          : "=&v"(v0), "=&v"(v1), "=&v"(v2), "=&v"(v3),
            "=&v"(v4), "=&v"(v5), "=&v"(v6), "=&v"(v7)
          : [p] "v"(hp)
          : "memory");
      char* hrow = smem + L_H + sb * 2048;
      const int sw = (sb & 7) << 4;
      *(u32x4*)(hrow + ((sc * 16 +    0) ^ sw)) = v0;
      *(u32x4*)(hrow + ((sc * 16 +  256) ^ sw)) = v1;
      *(u32x4*)(hrow + ((sc * 16 +  512) ^ sw)) = v2;
      *(u32x4*)(hrow + ((sc * 16 +  768) ^ sw)) = v3;
      *(u32x4*)(hrow + ((sc * 16 + 1024) ^ sw)) = v4;
      *(u32x4*)(hrow + ((sc * 16 + 1280) ^ sw)) = v5;
      *(u32x4*)(hrow + ((sc * 16 + 1536) ^ sw)) = v6;
      *(u32x4*)(hrow + ((sc * 16 + 1792) ^ sw)) = v7;
      __syncthreads();

      const char* hbase = smem + L_H + l15 * 2048;
      const int swh = (l15 & 7) << 4;
#pragma unroll
      for (int kc = 0; kc < 32; ++kc) {
        u32x4 a = *(const u32x4*)(hbase + ((kc * 64 + kg * 16) ^ swh));
        asm("v_mfma_f32_16x16x32_f16 %0, %1, %2, %0" : "+v"(acc) : "v"(a), "v"(bh[kc]));
      }
    }
    GUARD_POST(acc);

#pragma unroll
    for (int r = 0; r < 4; ++r)
      accl[g * 272 + (kg * 4 + r) * 17 + l15] = acc[r];
    __syncthreads();

    {
      float gf = accl[0 * 272 + eb * 17 + eu];
      float gi = accl[1 * 272 + eb * 17 + eu];
      float gc = accl[2 * 272 + eb * 17 + eu];
      float go = accl[3 * 272 + eb * 17 + eu];
      float f  = sigmoid_f(gf);
      float i  = sigmoid_f(gi);
      float cb = tanh_f(gc);
      float o  = sigmoid_f(go);
      float cn = f * c_reg + i * cb;
      c_reg = cn;
      float hn = o * tanh_f(cn);
      out[(((size_t)(bt * 16 + eb)) * NT + t) * NH + ug * 16 + eu] = hn;
      houtl[eb * 16 + eu] = f2h(hn);
    }
    __syncthreads();

    if (t + 1 < NT) {
      if (tid < 32) {
        u32x4 hv = *(const u32x4*)(houtl + tid * 8);
        unsigned short* dst = hglob + ((size_t)(buf * 4 + bt) * 16 + (tid >> 1)) * 1024
                            + ug * 16 + (tid & 1) * 8;
        asm volatile("global_store_dwordx4 %[p], %[v], off sc0 sc1\n\t"
                     "s_waitcnt vmcnt(0)"
                     :: [p] "v"(dst), [v] "v"(hv) : "memory");
      }
      if (tid == 0) {
        unsigned int* fp = flags + (t * 4 + bt) * 64 + ug;
        unsigned int one = 1u;
        asm volatile("global_store_dword %0, %1, off sc0 sc1"
                     :: "v"(fp), "v"(one) : "memory");
      }
    }
  }
}

// ---------------- persistent LSTM kernel: FAST path (xg in epilogue) -------

__global__ __launch_bounds__(256, 1) void lstm_persist_fast(
    const unsigned short* __restrict__ Whh,
    const unsigned short* __restrict__ xg,
    const float* __restrict__ bias,
    unsigned short* __restrict__ hglob,
    unsigned int* __restrict__ flags,
    float* __restrict__ out) {
  extern __shared__ char smem[];
  const int bid  = blockIdx.x;
  const int bt   = bid & 3;
  const int ug   = bid >> 2;
  const int tid  = threadIdx.x;
  const int g    = tid >> 6;
  const int lane = tid & 63;
  const int l15  = lane & 15;
  const int kg   = lane >> 4;

  cg::grid_group grid = cg::this_grid();

  __hip_atomic_store(&flags[bid * 256 + tid], 0u,
                     __ATOMIC_RELAXED, __HIP_MEMORY_SCOPE_AGENT);

  u32x4 bh[32];
  {
    const unsigned short* wr = Whh + ((size_t)(g * 1024 + ug * 16 + l15)) * 1024 + kg * 8;
#pragma unroll
    for (int kc = 0; kc < 32; ++kc) bh[kc] = *(const u32x4*)(wr + kc * 32);
  }
#pragma unroll
  for (int kc = 0; kc < 32; ++kc)
    asm volatile("" : "+v"(bh[kc]));
  const float bv = bias[g * 1024 + ug * 16 + l15];
  __syncthreads();

  grid.sync();   // flag zeros visible; xg written (stream order before launch)

  const int eb = tid >> 4;
  const int eu = tid & 15;
  float c_reg = 0.0f;

  float* accl = (float*)(smem + L_ACC_F);
  unsigned short* houtl = (unsigned short*)(smem + L_HOUT_F);

  const size_t xg_eb = ((size_t)(bt * 16 + eb) * 4) * 1024 + ug * 16 + eu;
  const size_t xg_tstr = (size_t)NB * 4 * 1024;

  for (int t = 0; t < NT; ++t) {
    const int buf = t & 1, pbuf = buf ^ 1;

    const unsigned short* qp = xg + (size_t)t * xg_tstr + xg_eb;
    unsigned short q0 = qp[0];
    unsigned short q1 = qp[1024];
    unsigned short q2 = qp[2048];
    unsigned short q3 = qp[3072];

    f32x4 acc = {bv, bv, bv, bv};
    GUARD_PRE(acc);

    if (t > 0) {
      if (g == 0) {
        const unsigned int* cp = flags + ((t - 1) * 4 + bt) * 64 + lane;
        unsigned int fv;
        while (true) {
          asm volatile("global_load_dword %0, %1, off sc0 sc1\n\ts_waitcnt vmcnt(0)"
                       : "=v"(fv) : "v"(cp) : "memory");
          if (__all(fv == 1u)) break;
          __builtin_amdgcn_s_sleep(2);
        }
      }
      __syncthreads();

      const int sb = tid >> 4, sc = tid & 15;
      const unsigned short* hp = hglob + ((size_t)(pbuf * 4 + bt) * 16 + sb) * 1024 + sc * 8;
      u32x4 v0, v1, v2, v3, v4, v5, v6, v7;
      asm volatile(
          "global_load_dwordx4 %0, %[p], off sc0 sc1\n\t"
          "global_load_dwordx4 %1, %[p], off offset:256 sc0 sc1\n\t"
          "global_load_dwordx4 %2, %[p], off offset:512 sc0 sc1\n\t"
          "global_load_dwordx4 %3, %[p], off offset:768 sc0 sc1\n\t"
          "global_load_dwordx4 %4, %[p], off offset:1024 sc0 sc1\n\t"
          "global_load_dwordx4 %5, %[p], off offset:1280 sc0 sc1\n\t"
          "global_load_dwordx4 %6, %[p], off offset:1536 sc0 sc1\n\t"
          "global_load_dwordx4 %7, %[p], off offset:1792 sc0 sc1\n\t"
          "s_waitcnt vmcnt(0)"
          : "=&v"(v0), "=&v"(v1), "=&v"(v2), "=&v"(v3),
            "=&v"(v4), "=&v"(v5), "=&v"(v6), "=&v"(v7)
          : [p] "v"(hp)
          : "memory");
      char* hrow = smem + L_H + sb * 2048;
      const int sw = (sb & 7) << 4;
      *(u32x4*)(hrow + ((sc * 16 +    0) ^ sw)) = v0;
      *(u32x4*)(hrow + ((sc * 16 +  256) ^ sw)) = v1;
      *(u32x4*)(hrow + ((sc * 16 +  512) ^ sw)) = v2;
      *(u32x4*)(hrow + ((sc * 16 +  768) ^ sw)) = v3;
      *(u32x4*)(hrow + ((sc * 16 + 1024) ^ sw)) = v4;
      *(u32x4*)(hrow + ((sc * 16 + 1280) ^ sw)) = v5;
      *(u32x4*)(hrow + ((sc * 16 + 1536) ^ sw)) = v6;
      *(u32x4*)(hrow + ((sc * 16 + 1792) ^ sw)) = v7;
      __syncthreads();

      const char* hbase = smem + L_H + l15 * 2048;
      const int swh = (l15 & 7) << 4;
#pragma unroll
      for (int kc = 0; kc < 32; ++kc) {
        u32x4 a = *(const u32x4*)(hbase + ((kc * 64 + kg * 16) ^ swh));
        asm("v_mfma_f32_16x16x32_f16 %0, %1, %2, %0" : "+v"(acc) : "v"(a), "v"(bh[kc]));
      }
    }
    GUARD_POST(acc);

#pragma unroll
    for (int r = 0; r < 4; ++r)
      accl[g * 272 + (kg * 4 + r) * 17 + l15] = acc[r];
    __syncthreads();

    // ---- pointwise epilogue: add xg here (pure VALU region) ----
    {
      float gf = accl[0 * 272 + eb * 17 + eu] + h2f(q0);
      float gi = accl[1 * 272 + eb * 17 + eu] + h2f(q1);
      float gc = accl[2 * 272 + eb * 17 + eu] + h2f(q2);
      float go = accl[3 * 272 + eb * 17 + eu] + h2f(q3);
      float f  = sigmoid_f(gf);
      float i  = sigmoid_f(gi);
      float cb = tanh_f(gc);
      float o  = sigmoid_f(go);
      float cn = f * c_reg + i * cb;
      c_reg = cn;
      float hn = o * tanh_f(cn);
      out[(((size_t)(bt * 16 + eb)) * NT + t) * NH + ug * 16 + eu] = hn;
      houtl[eb * 16 + eu] = f2h(hn);
    }
    __syncthreads();

    if (t + 1 < NT) {
      if (tid < 32) {
        u32x4 hv = *(const u32x4*)(houtl + tid * 8);
        unsigned short* dst = hglob + ((size_t)(buf * 4 + bt) * 16 + (tid >> 1)) * 1024
                            + ug * 16 + (tid & 1) * 8;
        asm volatile("global_store_dwordx4 %[p], %[v], off sc0 sc1\n\t"
                     "s_waitcnt vmcnt(0)"
                     :: [p] "v"(dst), [v] "v"(hv) : "memory");
      }
      if (tid == 0) {
        unsigned int* fp = flags + (t * 4 + bt) * 64 + ug;
        unsigned int one = 1u;
        asm volatile("global_store_dword %0, %1, off sc0 sc1"
                     :: "v"(fp), "v"(one) : "memory");
      }
    }
  }
}

// ---------------- host launcher ----------------

extern "C" void kernel_launch(void* const* d_in, const int* in_sizes, int n_in,
                              void* d_out, int out_size, void* d_ws, size_t ws_size,
                              hipStream_t stream) {
  (void)in_sizes; (void)n_in; (void)out_size;
  const float* x   = (const float*)d_in[0];
  const float* W_x = (const float*)d_in[1];
  const float* b_x = (const float*)d_in[2];
  const float* W_h = (const float*)d_in[3];
  const float* b_h = (const float*)d_in[4];
  const float* w_B = (const float*)d_in[5];
  const float* b_B = (const float*)d_in[6];
  float* out = (float*)d_out;

  char* ws = (char*)d_ws;
  unsigned short* Whh  = (unsigned short*)(ws + OFF_WHH);
  unsigned short* Wxh  = (unsigned short*)(ws + OFF_WXH);
  unsigned short* xhp  = (unsigned short*)(ws + OFF_XH);
  float*          bias = (float*)(ws + OFF_BIAS);
  unsigned short* hg   = (unsigned short*)(ws + OFF_HG);
  unsigned int*   flg  = (unsigned int*)(ws + OFF_FLG);
  unsigned short* xg   = (unsigned short*)(ws + OFF_XG);

  const size_t need_fast = (size_t)OFF_XG + (size_t)SZ_XG;
  const bool fast = (ws_size >= need_fast);

  hipFuncSetAttribute(reinterpret_cast<const void*>(lstm_persist_slow),
                      hipFuncAttributeMaxDynamicSharedMemorySize, LDS_SLOW);
  hipFuncSetAttribute(reinterpret_cast<const void*>(lstm_persist_fast),
                      hipFuncAttributeMaxDynamicSharedMemorySize, LDS_FAST);
  hipFuncSetAttribute(reinterpret_cast<const void*>(xg_gemm),
                      hipFuncAttributeMaxDynamicSharedMemorySize, XG_LDS);

  pack_w_kernel<<<dim3(6144), dim3(256), 0, stream>>>(W_h, W_x, Whh, Wxh);
  pack_x_kernel<<<dim3(4096), dim3(256), 0, stream>>>(x, xhp);
  prep_small_kernel<<<dim3(16), dim3(256), 0, stream>>>(b_x, b_h, w_B, b_B, bias);

  if (fast) {
    xg_gemm<<<dim3(1024), dim3(256), XG_LDS, stream>>>(Wxh, xhp, xg);
    void* kargs[] = {(void*)&Whh, (void*)&xg, (void*)&bias,
                     (void*)&hg, (void*)&flg, (void*)&out};
    hipLaunchCooperativeKernel(reinterpret_cast<void*>(lstm_persist_fast),
                               dim3(256), dim3(256), kargs, LDS_FAST, stream);
  } else {
    void* kargs[] = {(void*)&Whh, (void*)&Wxh, (void*)&xhp, (void*)&bias,
                     (void*)&hg, (void*)&flg, (void*)&out};
    hipLaunchCooperativeKernel(reinterpret_cast<void*>(lstm_persist_slow),
                               dim3(256), dim3(256), kargs, LDS_SLOW, stream);
  }
}